// Round 1
// baseline (410.068 us; speedup 1.0000x reference)
//
#include <hip/hip_runtime.h>

// ShallowRBF: x(8192x2048), centers(4096x2048), beta(4096), W(1000x4096), b(1000)
// out(8192x1000) = softmax-ish RBF: e = exp(-beta*||x-c||); out = (e @ W^T)/rowsum(e) + b
//
// Plan: fp32 norms + bf16 MFMA GEMMs (m97-style 128x128 tile, BK=64,
// global_load_lds width 16, XOR-swizzled LDS chunks).

#define BB 8192
#define DD 2048
#define CC 4096
#define KK 1000
#define KP 1024

typedef unsigned short u16;
typedef __bf16 bf16x8 __attribute__((ext_vector_type(8)));
typedef float f32x4 __attribute__((ext_vector_type(4)));

typedef const void __attribute__((address_space(1)))* gvp_t;
typedef void __attribute__((address_space(3)))* lvp_t;

__device__ __forceinline__ u16 f2bf(float f) {
  union { float f; unsigned u; } v; v.f = f;
  return (u16)((v.u + 0x7fffu + ((v.u >> 16) & 1u)) >> 16);  // RNE
}

// ---- prep: row norms (fp32) + bf16 casts of x and centers ----
__global__ void prep_norm_cast(const float* __restrict__ x, const float* __restrict__ cen,
                               u16* __restrict__ xb, u16* __restrict__ cb,
                               float* __restrict__ x2, float* __restrict__ c2) {
  int row = blockIdx.x;
  const float* src;
  u16* dst;
  float* nrm;
  if (row < BB) {
    src = x + (size_t)row * DD; dst = xb + (size_t)row * DD; nrm = x2 + row;
  } else {
    int r = row - BB;
    src = cen + (size_t)r * DD; dst = cb + (size_t)r * DD; nrm = c2 + r;
  }
  int t = threadIdx.x;
  float s = 0.f;
#pragma unroll
  for (int m = 0; m < 2; ++m) {
    int idx = t + 256 * m;
    float4 v = reinterpret_cast<const float4*>(src)[idx];
    s += v.x * v.x + v.y * v.y + v.z * v.z + v.w * v.w;
    reinterpret_cast<ushort4*>(dst)[idx] =
        make_ushort4(f2bf(v.x), f2bf(v.y), f2bf(v.z), f2bf(v.w));
  }
#pragma unroll
  for (int off = 1; off < 64; off <<= 1) s += __shfl_xor(s, off);
  __shared__ float red[4];
  if ((t & 63) == 0) red[t >> 6] = s;
  __syncthreads();
  if (t == 0) *nrm = red[0] + red[1] + red[2] + red[3];
}

// ---- prep: W cast to bf16, padded to 1024 rows (zeros) ----
__global__ void prep_wcast(const float* __restrict__ W, u16* __restrict__ wb) {
  int row = blockIdx.x;  // 0..1023
  int t = threadIdx.x;
  ushort4* dst = reinterpret_cast<ushort4*>(wb + (size_t)row * CC);
  if (row < KK) {
    const float4* src = reinterpret_cast<const float4*>(W + (size_t)row * CC);
#pragma unroll
    for (int m = 0; m < 4; ++m) {
      float4 v = src[t + 256 * m];
      dst[t + 256 * m] = make_ushort4(f2bf(v.x), f2bf(v.y), f2bf(v.z), f2bf(v.w));
    }
  } else {
#pragma unroll
    for (int m = 0; m < 4; ++m) dst[t + 256 * m] = make_ushort4(0, 0, 0, 0);
  }
}

// ---- GEMM1: dot = x @ centers^T; epilogue -> e = exp(-beta*dist) (bf16) + rowsum ----
__global__ void gemm1_rbf(const u16* __restrict__ Abf, const u16* __restrict__ Bbf,
                          const float* __restrict__ x2, const float* __restrict__ c2,
                          const float* __restrict__ beta, u16* __restrict__ Ebf,
                          float* __restrict__ rowsum) {
  constexpr int Kd = DD;
  __shared__ __align__(16) char smem[32768];  // A: 128x64 bf16 (16KB) + B: same

  const int t = threadIdx.x;
  const int lane = t & 63;
  const int wave = t >> 6;
  const int wr = wave >> 1, wc = wave & 1;
  const int l15 = lane & 15, quad = lane >> 4;

  const int rowBase = blockIdx.y * 128;
  const int colBase = blockIdx.x * 128;

  f32x4 acc[4][4];
  f32x4 z4 = {0.f, 0.f, 0.f, 0.f};
#pragma unroll
  for (int i = 0; i < 4; ++i)
#pragma unroll
    for (int j = 0; j < 4; ++j) acc[i][j] = z4;

  const int sr = t >> 3;  // staging row 0..31 (per 32-row group)
  const int sc = t & 7;   // staging 16B-chunk 0..7

  for (int kc = 0; kc < Kd; kc += 64) {
#pragma unroll
    for (int it = 0; it < 4; ++it) {
      int r = sr + 32 * it;
      int sw = (sc ^ (r & 7)) * 8;  // swizzled source chunk (elements)
      const u16* ga = Abf + (size_t)(rowBase + r) * Kd + kc + sw;
      const u16* gb = Bbf + (size_t)(colBase + r) * Kd + kc + sw;
      char* la = smem + it * 4096 + t * 16;
      char* lb = smem + 16384 + it * 4096 + t * 16;
      __builtin_amdgcn_global_load_lds((gvp_t)ga, (lvp_t)la, 16, 0, 0);
      __builtin_amdgcn_global_load_lds((gvp_t)gb, (lvp_t)lb, 16, 0, 0);
    }
    __syncthreads();
#pragma unroll
    for (int ks = 0; ks < 2; ++ks) {
      bf16x8 af[4], bfr[4];
#pragma unroll
      for (int i = 0; i < 4; ++i) {
        int r = wr * 64 + i * 16 + l15;
        int slot = (ks * 4 + quad) ^ (r & 7);
        af[i] = *(const bf16x8*)(smem + r * 128 + slot * 16);
      }
#pragma unroll
      for (int j = 0; j < 4; ++j) {
        int r = wc * 64 + j * 16 + l15;
        int slot = (ks * 4 + quad) ^ (r & 7);
        bfr[j] = *(const bf16x8*)(smem + 16384 + r * 128 + slot * 16);
      }
#pragma unroll
      for (int j = 0; j < 4; ++j)
#pragma unroll
        for (int i = 0; i < 4; ++i)
          acc[i][j] = __builtin_amdgcn_mfma_f32_16x16x32_bf16(af[i], bfr[j], acc[i][j], 0, 0, 0);
    }
    __syncthreads();
  }

  // epilogue: sq = x2 + c2 - 2 dot; e = exp(-beta*sqrt(max(sq,0)))
  const int rbase = rowBase + wr * 64;
  const int cbase = colBase + wc * 64;
  float x2r[4][4];
#pragma unroll
  for (int i = 0; i < 4; ++i)
#pragma unroll
    for (int r = 0; r < 4; ++r) x2r[i][r] = x2[rbase + i * 16 + quad * 4 + r];

  float rs[4][4];
#pragma unroll
  for (int i = 0; i < 4; ++i)
#pragma unroll
    for (int r = 0; r < 4; ++r) rs[i][r] = 0.f;

#pragma unroll
  for (int j = 0; j < 4; ++j) {
    int cg = cbase + j * 16 + l15;
    float c2v = c2[cg];
    float bet = beta[cg];
#pragma unroll
    for (int i = 0; i < 4; ++i) {
      int rg0 = rbase + i * 16 + quad * 4;
#pragma unroll
      for (int r = 0; r < 4; ++r) {
        float d = acc[i][j][r];
        float sq = fmaxf(x2r[i][r] + c2v - 2.0f * d, 0.0f);
        float e = expf(-bet * sqrtf(sq));
        Ebf[(size_t)(rg0 + r) * CC + cg] = f2bf(e);
        rs[i][r] += e;
      }
    }
  }
#pragma unroll
  for (int i = 0; i < 4; ++i)
#pragma unroll
    for (int r = 0; r < 4; ++r) {
      float v = rs[i][r];
      v += __shfl_xor(v, 1);
      v += __shfl_xor(v, 2);
      v += __shfl_xor(v, 4);
      v += __shfl_xor(v, 8);
      if (l15 == 0) atomicAdd(&rowsum[rbase + i * 16 + quad * 4 + r], v);
    }
}

// ---- GEMM2: out = (e @ W^T)/rowsum + bias ----
__global__ void gemm2_out(const u16* __restrict__ Ebf, const u16* __restrict__ Wbf,
                          const float* __restrict__ rowsum, const float* __restrict__ bias,
                          float* __restrict__ out) {
  constexpr int Kd = CC;
  __shared__ __align__(16) char smem[32768];

  const int t = threadIdx.x;
  const int lane = t & 63;
  const int wave = t >> 6;
  const int wr = wave >> 1, wc = wave & 1;
  const int l15 = lane & 15, quad = lane >> 4;

  const int rowBase = blockIdx.y * 128;
  const int colBase = blockIdx.x * 128;

  f32x4 acc[4][4];
  f32x4 z4 = {0.f, 0.f, 0.f, 0.f};
#pragma unroll
  for (int i = 0; i < 4; ++i)
#pragma unroll
    for (int j = 0; j < 4; ++j) acc[i][j] = z4;

  const int sr = t >> 3;
  const int sc = t & 7;

  for (int kc = 0; kc < Kd; kc += 64) {
#pragma unroll
    for (int it = 0; it < 4; ++it) {
      int r = sr + 32 * it;
      int sw = (sc ^ (r & 7)) * 8;
      const u16* ga = Ebf + (size_t)(rowBase + r) * Kd + kc + sw;
      const u16* gb = Wbf + (size_t)(colBase + r) * Kd + kc + sw;
      char* la = smem + it * 4096 + t * 16;
      char* lb = smem + 16384 + it * 4096 + t * 16;
      __builtin_amdgcn_global_load_lds((gvp_t)ga, (lvp_t)la, 16, 0, 0);
      __builtin_amdgcn_global_load_lds((gvp_t)gb, (lvp_t)lb, 16, 0, 0);
    }
    __syncthreads();
#pragma unroll
    for (int ks = 0; ks < 2; ++ks) {
      bf16x8 af[4], bfr[4];
#pragma unroll
      for (int i = 0; i < 4; ++i) {
        int r = wr * 64 + i * 16 + l15;
        int slot = (ks * 4 + quad) ^ (r & 7);
        af[i] = *(const bf16x8*)(smem + r * 128 + slot * 16);
      }
#pragma unroll
      for (int j = 0; j < 4; ++j) {
        int r = wc * 64 + j * 16 + l15;
        int slot = (ks * 4 + quad) ^ (r & 7);
        bfr[j] = *(const bf16x8*)(smem + 16384 + r * 128 + slot * 16);
      }
#pragma unroll
      for (int j = 0; j < 4; ++j)
#pragma unroll
        for (int i = 0; i < 4; ++i)
          acc[i][j] = __builtin_amdgcn_mfma_f32_16x16x32_bf16(af[i], bfr[j], acc[i][j], 0, 0, 0);
    }
    __syncthreads();
  }

  const int rbase = rowBase + wr * 64;
  const int cbase = colBase + wc * 64;
  float inv[4][4];
#pragma unroll
  for (int i = 0; i < 4; ++i)
#pragma unroll
    for (int r = 0; r < 4; ++r) inv[i][r] = 1.0f / rowsum[rbase + i * 16 + quad * 4 + r];

#pragma unroll
  for (int j = 0; j < 4; ++j) {
    int cg = cbase + j * 16 + l15;
    if (cg < KK) {
      float bv = bias[cg];
#pragma unroll
      for (int i = 0; i < 4; ++i) {
        int rg0 = rbase + i * 16 + quad * 4;
#pragma unroll
        for (int r = 0; r < 4; ++r)
          out[(size_t)(rg0 + r) * KK + cg] = acc[i][j][r] * inv[i][r] + bv;
      }
    }
  }
}

// ---- workspace layout (bytes) ----
#define OFF_XB 0u                    // 8192*2048*2 = 33554432
#define OFF_CB 33554432u             // 4096*2048*2 = 16777216
#define OFF_WB 50331648u             // 1024*4096*2 = 8388608
#define OFF_EB 58720256u             // 8192*4096*2 = 67108864
#define OFF_X2 125829120u            // 8192*4
#define OFF_C2 125861888u            // 4096*4
#define OFF_RS 125878272u            // 8192*4

extern "C" void kernel_launch(void* const* d_in, const int* in_sizes, int n_in,
                              void* d_out, int out_size, void* d_ws, size_t ws_size,
                              hipStream_t stream) {
  const float* x = (const float*)d_in[0];
  const float* cen = (const float*)d_in[1];
  const float* beta = (const float*)d_in[2];
  const float* W = (const float*)d_in[3];
  const float* bias = (const float*)d_in[4];
  float* out = (float*)d_out;
  char* ws = (char*)d_ws;

  u16* xb = (u16*)(ws + OFF_XB);
  u16* cb = (u16*)(ws + OFF_CB);
  u16* wb = (u16*)(ws + OFF_WB);
  u16* eb = (u16*)(ws + OFF_EB);
  float* x2 = (float*)(ws + OFF_X2);
  float* c2 = (float*)(ws + OFF_C2);
  float* rowsum = (float*)(ws + OFF_RS);

  hipMemsetAsync(rowsum, 0, BB * sizeof(float), stream);
  prep_norm_cast<<<BB + CC, 256, 0, stream>>>(x, cen, xb, cb, x2, c2);
  prep_wcast<<<KP, 256, 0, stream>>>(W, wb);
  gemm1_rbf<<<dim3(CC / 128, BB / 128), 256, 0, stream>>>(xb, cb, x2, c2, beta, eb, rowsum);
  gemm2_out<<<dim3(KP / 128, BB / 128), 256, 0, stream>>>(eb, wb, rowsum, bias, out);
}

// Round 2
// 390.232 us; speedup vs baseline: 1.0508x; 1.0508x over previous
//
#include <hip/hip_runtime.h>

// ShallowRBF: x(8192x2048), centers(4096x2048), beta(4096), W(1000x4096), b(1000)
// out = (exp(-beta*||x-c||) @ W^T) / rowsum + b
//
// R2: 32x32x16 bf16 MFMA. gemm1: 256x128 block, 128x64 wave-tile (4x2 of 32x32),
// LDS 48KB, BK=64. Rowsum moved to its own memory-bound kernel (no atomics).
// gemm2: 128x128 block, 64x64 wave-tile (2x2 of 32x32).

#define BB 8192
#define DD 2048
#define CC 4096
#define KK 1000
#define KP 1024

typedef unsigned short u16;
typedef __bf16 bf16x8 __attribute__((ext_vector_type(8)));
typedef float f32x16 __attribute__((ext_vector_type(16)));

typedef const void __attribute__((address_space(1)))* gvp_t;
typedef void __attribute__((address_space(3)))* lvp_t;

__device__ __forceinline__ u16 f2bf(float f) {
  union { float f; unsigned u; } v; v.f = f;
  return (u16)((v.u + 0x7fffu + ((v.u >> 16) & 1u)) >> 16);  // RNE
}
__device__ __forceinline__ float bf2f(u16 h) {
  union { unsigned u; float f; } v; v.u = ((unsigned)h) << 16;
  return v.f;
}

// ---- prep: row norms (fp32) + bf16 casts of x and centers ----
__global__ void prep_norm_cast(const float* __restrict__ x, const float* __restrict__ cen,
                               u16* __restrict__ xb, u16* __restrict__ cb,
                               float* __restrict__ x2, float* __restrict__ c2) {
  int row = blockIdx.x;
  const float* src;
  u16* dst;
  float* nrm;
  if (row < BB) {
    src = x + (size_t)row * DD; dst = xb + (size_t)row * DD; nrm = x2 + row;
  } else {
    int r = row - BB;
    src = cen + (size_t)r * DD; dst = cb + (size_t)r * DD; nrm = c2 + r;
  }
  int t = threadIdx.x;
  float s = 0.f;
#pragma unroll
  for (int m = 0; m < 2; ++m) {
    int idx = t + 256 * m;
    float4 v = reinterpret_cast<const float4*>(src)[idx];
    s += v.x * v.x + v.y * v.y + v.z * v.z + v.w * v.w;
    reinterpret_cast<ushort4*>(dst)[idx] =
        make_ushort4(f2bf(v.x), f2bf(v.y), f2bf(v.z), f2bf(v.w));
  }
#pragma unroll
  for (int off = 1; off < 64; off <<= 1) s += __shfl_xor(s, off);
  __shared__ float red[4];
  if ((t & 63) == 0) red[t >> 6] = s;
  __syncthreads();
  if (t == 0) *nrm = red[0] + red[1] + red[2] + red[3];
}

// ---- prep: W cast to bf16, padded to 1024 rows (zeros) ----
__global__ void prep_wcast(const float* __restrict__ W, u16* __restrict__ wb) {
  int row = blockIdx.x;  // 0..1023
  int t = threadIdx.x;
  ushort4* dst = reinterpret_cast<ushort4*>(wb + (size_t)row * CC);
  if (row < KK) {
    const float4* src = reinterpret_cast<const float4*>(W + (size_t)row * CC);
#pragma unroll
    for (int m = 0; m < 4; ++m) {
      float4 v = src[t + 256 * m];
      dst[t + 256 * m] = make_ushort4(f2bf(v.x), f2bf(v.y), f2bf(v.z), f2bf(v.w));
    }
  } else {
#pragma unroll
    for (int m = 0; m < 4; ++m) dst[t + 256 * m] = make_ushort4(0, 0, 0, 0);
  }
}

// ---- GEMM1: 256x128 tile; epilogue e = exp(-beta*dist) -> Ebf ----
__global__ __launch_bounds__(256, 2)
void gemm1_rbf(const u16* __restrict__ Abf, const u16* __restrict__ Bbf,
               const float* __restrict__ x2, const float* __restrict__ c2,
               const float* __restrict__ beta, u16* __restrict__ Ebf) {
  constexpr int Kd = DD;
  __shared__ __align__(16) char smem[49152];  // A: 256x64 bf16 (32KB) + B: 128x64 (16KB)

  const int t = threadIdx.x;
  const int lane = t & 63;
  const int wave = t >> 6;
  const int wr = wave >> 1, wc = wave & 1;  // wave-tile: rows wr*128.., cols wc*64..
  const int l31 = lane & 31, khalf = lane >> 5;

  const int rowBase = blockIdx.y * 256;
  const int colBase = blockIdx.x * 128;

  f32x16 acc[4][2];
#pragma unroll
  for (int i = 0; i < 4; ++i)
#pragma unroll
    for (int j = 0; j < 2; ++j) acc[i][j] = 0.f;

  // staging: thread t -> row t>>3 (+32*it), LDS slot t&7 (XOR swizzled source chunk)
  const int sr = t >> 3;
  const int srcChunkOff = ((t & 7) ^ ((t >> 3) & 7)) * 8;  // elements
  const u16* gA0 = Abf + (size_t)(rowBase + sr) * Kd + srcChunkOff;
  const u16* gB0 = Bbf + (size_t)(colBase + sr) * Kd + srcChunkOff;

  // frag read bases
  const int xorv = l31 & 7;

  for (int kc = 0; kc < Kd; kc += 64) {
#pragma unroll
    for (int it = 0; it < 8; ++it) {
      const u16* ga = gA0 + (size_t)(32 * it) * Kd + kc;
      __builtin_amdgcn_global_load_lds((gvp_t)ga, (lvp_t)(smem + it * 4096 + t * 16), 16, 0, 0);
    }
#pragma unroll
    for (int it = 0; it < 4; ++it) {
      const u16* gb = gB0 + (size_t)(32 * it) * Kd + kc;
      __builtin_amdgcn_global_load_lds((gvp_t)gb, (lvp_t)(smem + 32768 + it * 4096 + t * 16), 16, 0, 0);
    }
    __syncthreads();
#pragma unroll
    for (int ks = 0; ks < 4; ++ks) {
      const int slot = ((ks * 2 + khalf) ^ xorv) * 16;
      bf16x8 af[4], bfr[2];
#pragma unroll
      for (int i = 0; i < 4; ++i) {
        int r = wr * 128 + i * 32 + l31;
        af[i] = *(const bf16x8*)(smem + r * 128 + slot);
      }
#pragma unroll
      for (int j = 0; j < 2; ++j) {
        int r = wc * 64 + j * 32 + l31;
        bfr[j] = *(const bf16x8*)(smem + 32768 + r * 128 + slot);
      }
#pragma unroll
      for (int j = 0; j < 2; ++j)
#pragma unroll
        for (int i = 0; i < 4; ++i)
          acc[i][j] = __builtin_amdgcn_mfma_f32_32x32x16_bf16(af[i], bfr[j], acc[i][j], 0, 0, 0);
    }
    __syncthreads();
  }

  // epilogue: C/D layout col=lane&31, row=(reg&3)+8*(reg>>2)+4*(lane>>5)
  const int rbase = rowBase + wr * 128 + 4 * khalf;
  const int cbase = colBase + wc * 64;
  float c2v[2], bet[2];
  int gcol[2];
#pragma unroll
  for (int j = 0; j < 2; ++j) {
    gcol[j] = cbase + j * 32 + l31;
    c2v[j] = c2[gcol[j]];
    bet[j] = beta[gcol[j]];
  }
#pragma unroll
  for (int i = 0; i < 4; ++i) {
#pragma unroll
    for (int reg = 0; reg < 16; ++reg) {
      int grow = rbase + i * 32 + (reg & 3) + 8 * (reg >> 2);
      float x2v = x2[grow];
#pragma unroll
      for (int j = 0; j < 2; ++j) {
        float d = acc[i][j][reg];
        float sq = fmaxf(x2v + c2v[j] - 2.0f * d, 0.0f);
        float e = __expf(-bet[j] * __builtin_amdgcn_sqrtf(sq));
        Ebf[(size_t)grow * CC + gcol[j]] = f2bf(e);
      }
    }
  }
}

// ---- rowsum: one wave per row of Ebf ----
__global__ void rowsum_k(const u16* __restrict__ Ebf, float* __restrict__ rowsum) {
  const int lane = threadIdx.x & 63;
  const int row = blockIdx.x * 4 + (threadIdx.x >> 6);
  const uint4* p = reinterpret_cast<const uint4*>(Ebf + (size_t)row * CC);
  float s = 0.f;
#pragma unroll
  for (int it = 0; it < 8; ++it) {
    uint4 v = p[lane + 64 * it];
    unsigned w[4] = {v.x, v.y, v.z, v.w};
#pragma unroll
    for (int q = 0; q < 4; ++q) {
      union { unsigned u; float f; } lo, hi;
      lo.u = w[q] << 16;
      hi.u = w[q] & 0xffff0000u;
      s += lo.f + hi.f;
    }
  }
#pragma unroll
  for (int off = 1; off < 64; off <<= 1) s += __shfl_xor(s, off);
  if (lane == 0) rowsum[row] = s;
}

// ---- GEMM2: out = (E @ W^T)/rowsum + bias; 128x128 tile, 2x2 of 32x32 ----
__global__ __launch_bounds__(256, 3)
void gemm2_out(const u16* __restrict__ Ebf, const u16* __restrict__ Wbf,
               const float* __restrict__ rowsum, const float* __restrict__ bias,
               float* __restrict__ out) {
  constexpr int Kd = CC;
  __shared__ __align__(16) char smem[32768];

  const int t = threadIdx.x;
  const int lane = t & 63;
  const int wave = t >> 6;
  const int wr = wave >> 1, wc = wave & 1;
  const int l31 = lane & 31, khalf = lane >> 5;

  const int rowBase = blockIdx.y * 128;
  const int colBase = blockIdx.x * 128;

  f32x16 acc[2][2];
#pragma unroll
  for (int i = 0; i < 2; ++i)
#pragma unroll
    for (int j = 0; j < 2; ++j) acc[i][j] = 0.f;

  const int sr = t >> 3;
  const int srcChunkOff = ((t & 7) ^ ((t >> 3) & 7)) * 8;
  const u16* gA0 = Ebf + (size_t)(rowBase + sr) * Kd + srcChunkOff;
  const u16* gB0 = Wbf + (size_t)(colBase + sr) * Kd + srcChunkOff;
  const int xorv = l31 & 7;

  for (int kc = 0; kc < Kd; kc += 64) {
#pragma unroll
    for (int it = 0; it < 4; ++it) {
      const u16* ga = gA0 + (size_t)(32 * it) * Kd + kc;
      __builtin_amdgcn_global_load_lds((gvp_t)ga, (lvp_t)(smem + it * 4096 + t * 16), 16, 0, 0);
    }
#pragma unroll
    for (int it = 0; it < 4; ++it) {
      const u16* gb = gB0 + (size_t)(32 * it) * Kd + kc;
      __builtin_amdgcn_global_load_lds((gvp_t)gb, (lvp_t)(smem + 16384 + it * 4096 + t * 16), 16, 0, 0);
    }
    __syncthreads();
#pragma unroll
    for (int ks = 0; ks < 4; ++ks) {
      const int slot = ((ks * 2 + khalf) ^ xorv) * 16;
      bf16x8 af[2], bfr[2];
#pragma unroll
      for (int i = 0; i < 2; ++i) {
        int r = wr * 64 + i * 32 + l31;
        af[i] = *(const bf16x8*)(smem + r * 128 + slot);
      }
#pragma unroll
      for (int j = 0; j < 2; ++j) {
        int r = wc * 64 + j * 32 + l31;
        bfr[j] = *(const bf16x8*)(smem + 16384 + r * 128 + slot);
      }
#pragma unroll
      for (int j = 0; j < 2; ++j)
#pragma unroll
        for (int i = 0; i < 2; ++i)
          acc[i][j] = __builtin_amdgcn_mfma_f32_32x32x16_bf16(af[i], bfr[j], acc[i][j], 0, 0, 0);
    }
    __syncthreads();
  }

  const int rbase = rowBase + wr * 64 + 4 * khalf;
  const int cbase = colBase + wc * 64;
  int gcol[2];
  float bv[2];
#pragma unroll
  for (int j = 0; j < 2; ++j) {
    gcol[j] = cbase + j * 32 + l31;
    bv[j] = (gcol[j] < KK) ? bias[gcol[j]] : 0.f;
  }
#pragma unroll
  for (int i = 0; i < 2; ++i) {
#pragma unroll
    for (int reg = 0; reg < 16; ++reg) {
      int grow = rbase + i * 32 + (reg & 3) + 8 * (reg >> 2);
      float inv = 1.0f / rowsum[grow];
#pragma unroll
      for (int j = 0; j < 2; ++j) {
        if (gcol[j] < KK)
          out[(size_t)grow * KK + gcol[j]] = acc[i][j][reg] * inv + bv[j];
      }
    }
  }
}

// ---- workspace layout (bytes) ----
#define OFF_XB 0u                    // 8192*2048*2 = 33554432
#define OFF_CB 33554432u             // 4096*2048*2 = 16777216
#define OFF_WB 50331648u             // 1024*4096*2 = 8388608
#define OFF_EB 58720256u             // 8192*4096*2 = 67108864
#define OFF_X2 125829120u            // 8192*4
#define OFF_C2 125861888u            // 4096*4
#define OFF_RS 125878272u            // 8192*4

extern "C" void kernel_launch(void* const* d_in, const int* in_sizes, int n_in,
                              void* d_out, int out_size, void* d_ws, size_t ws_size,
                              hipStream_t stream) {
  const float* x = (const float*)d_in[0];
  const float* cen = (const float*)d_in[1];
  const float* beta = (const float*)d_in[2];
  const float* W = (const float*)d_in[3];
  const float* bias = (const float*)d_in[4];
  float* out = (float*)d_out;
  char* ws = (char*)d_ws;

  u16* xb = (u16*)(ws + OFF_XB);
  u16* cb = (u16*)(ws + OFF_CB);
  u16* wb = (u16*)(ws + OFF_WB);
  u16* eb = (u16*)(ws + OFF_EB);
  float* x2 = (float*)(ws + OFF_X2);
  float* c2 = (float*)(ws + OFF_C2);
  float* rowsum = (float*)(ws + OFF_RS);

  prep_norm_cast<<<BB + CC, 256, 0, stream>>>(x, cen, xb, cb, x2, c2);
  prep_wcast<<<KP, 256, 0, stream>>>(W, wb);
  gemm1_rbf<<<dim3(CC / 128, BB / 256), 256, 0, stream>>>(xb, cb, x2, c2, beta, eb);
  rowsum_k<<<BB / 4, 256, 0, stream>>>(eb, rowsum);
  gemm2_out<<<dim3(KP / 128, BB / 128), 256, 0, stream>>>(eb, wb, rowsum, bias, out);
}

// Round 3
// 387.314 us; speedup vs baseline: 1.0587x; 1.0075x over previous
//
#include <hip/hip_runtime.h>

// ShallowRBF: x(8192x2048), centers(4096x2048), beta(4096), W(1000x4096), b(1000)
// out = (exp(-beta*||x-c||) @ W^T) / rowsum + b
//
// R3: fix LDS bank conflicts. Swizzle p(r,c) = c ^ (r&7) ^ (((r>>3)&3)<<1):
// conflict-free for 32-row-span frag reads under both consecutive-8 and
// strided-8 lane phasings (R2's c^(r&7) gave +4 cyc/ds_read_b128 = 1.26e7).

#define BB 8192
#define DD 2048
#define CC 4096
#define KK 1000
#define KP 1024

typedef unsigned short u16;
typedef __bf16 bf16x8 __attribute__((ext_vector_type(8)));
typedef float f32x16 __attribute__((ext_vector_type(16)));

typedef const void __attribute__((address_space(1)))* gvp_t;
typedef void __attribute__((address_space(3)))* lvp_t;

__device__ __forceinline__ u16 f2bf(float f) {
  union { float f; unsigned u; } v; v.f = f;
  return (u16)((v.u + 0x7fffu + ((v.u >> 16) & 1u)) >> 16);  // RNE
}

// ---- prep: row norms (fp32) + bf16 casts of x and centers ----
__global__ void prep_norm_cast(const float* __restrict__ x, const float* __restrict__ cen,
                               u16* __restrict__ xb, u16* __restrict__ cb,
                               float* __restrict__ x2, float* __restrict__ c2) {
  int row = blockIdx.x;
  const float* src;
  u16* dst;
  float* nrm;
  if (row < BB) {
    src = x + (size_t)row * DD; dst = xb + (size_t)row * DD; nrm = x2 + row;
  } else {
    int r = row - BB;
    src = cen + (size_t)r * DD; dst = cb + (size_t)r * DD; nrm = c2 + r;
  }
  int t = threadIdx.x;
  float s = 0.f;
#pragma unroll
  for (int m = 0; m < 2; ++m) {
    int idx = t + 256 * m;
    float4 v = reinterpret_cast<const float4*>(src)[idx];
    s += v.x * v.x + v.y * v.y + v.z * v.z + v.w * v.w;
    reinterpret_cast<ushort4*>(dst)[idx] =
        make_ushort4(f2bf(v.x), f2bf(v.y), f2bf(v.z), f2bf(v.w));
  }
#pragma unroll
  for (int off = 1; off < 64; off <<= 1) s += __shfl_xor(s, off);
  __shared__ float red[4];
  if ((t & 63) == 0) red[t >> 6] = s;
  __syncthreads();
  if (t == 0) *nrm = red[0] + red[1] + red[2] + red[3];
}

// ---- prep: W cast to bf16, padded to 1024 rows (zeros) ----
__global__ void prep_wcast(const float* __restrict__ W, u16* __restrict__ wb) {
  int row = blockIdx.x;  // 0..1023
  int t = threadIdx.x;
  ushort4* dst = reinterpret_cast<ushort4*>(wb + (size_t)row * CC);
  if (row < KK) {
    const float4* src = reinterpret_cast<const float4*>(W + (size_t)row * CC);
#pragma unroll
    for (int m = 0; m < 4; ++m) {
      float4 v = src[t + 256 * m];
      dst[t + 256 * m] = make_ushort4(f2bf(v.x), f2bf(v.y), f2bf(v.z), f2bf(v.w));
    }
  } else {
#pragma unroll
    for (int m = 0; m < 4; ++m) dst[t + 256 * m] = make_ushort4(0, 0, 0, 0);
  }
}

// ---- GEMM1: 256x128 tile; epilogue e = exp(-beta*dist) -> Ebf ----
__global__ __launch_bounds__(256, 3)
void gemm1_rbf(const u16* __restrict__ Abf, const u16* __restrict__ Bbf,
               const float* __restrict__ x2, const float* __restrict__ c2,
               const float* __restrict__ beta, u16* __restrict__ Ebf) {
  constexpr int Kd = DD;
  __shared__ __align__(16) char smem[49152];  // A: 256x64 bf16 (32KB) + B: 128x64 (16KB)

  const int t = threadIdx.x;
  const int lane = t & 63;
  const int wave = t >> 6;
  const int wr = wave >> 1, wc = wave & 1;  // wave-tile: rows wr*128.., cols wc*64..
  const int l31 = lane & 31, khalf = lane >> 5;

  const int rowBase = blockIdx.y * 256;
  const int colBase = blockIdx.x * 128;

  f32x16 acc[4][2];
#pragma unroll
  for (int i = 0; i < 4; ++i)
#pragma unroll
    for (int j = 0; j < 2; ++j) acc[i][j] = 0.f;

  // staging: thread t -> phys (row t>>3 (+32*it), chunk t&7); fetches logical
  // chunk (t&7) ^ f(row), f(r) = (r&7) ^ (((r>>3)&3)<<1), invariant in it.
  const int sr = t >> 3;
  const int fstage = ((t >> 3) & 7) ^ (((t >> 6) & 3) << 1);
  const int srcChunkOff = ((t & 7) ^ fstage) * 8;  // elements
  const u16* gA0 = Abf + (size_t)(rowBase + sr) * Kd + srcChunkOff;
  const u16* gB0 = Bbf + (size_t)(colBase + sr) * Kd + srcChunkOff;

  // frag read: lane needs (row base+l31, chunk ks*2+khalf) at phys chunk c ^ fv
  const int fv = (l31 & 7) ^ (((l31 >> 3) & 3) << 1);

  for (int kc = 0; kc < Kd; kc += 64) {
#pragma unroll
    for (int it = 0; it < 8; ++it) {
      const u16* ga = gA0 + (size_t)(32 * it) * Kd + kc;
      __builtin_amdgcn_global_load_lds((gvp_t)ga, (lvp_t)(smem + it * 4096 + t * 16), 16, 0, 0);
    }
#pragma unroll
    for (int it = 0; it < 4; ++it) {
      const u16* gb = gB0 + (size_t)(32 * it) * Kd + kc;
      __builtin_amdgcn_global_load_lds((gvp_t)gb, (lvp_t)(smem + 32768 + it * 4096 + t * 16), 16, 0, 0);
    }
    __syncthreads();
#pragma unroll
    for (int ks = 0; ks < 4; ++ks) {
      const int slot = ((ks * 2 + khalf) ^ fv) * 16;
      bf16x8 af[4], bfr[2];
#pragma unroll
      for (int i = 0; i < 4; ++i) {
        int r = wr * 128 + i * 32 + l31;
        af[i] = *(const bf16x8*)(smem + r * 128 + slot);
      }
#pragma unroll
      for (int j = 0; j < 2; ++j) {
        int r = wc * 64 + j * 32 + l31;
        bfr[j] = *(const bf16x8*)(smem + 32768 + r * 128 + slot);
      }
#pragma unroll
      for (int j = 0; j < 2; ++j)
#pragma unroll
        for (int i = 0; i < 4; ++i)
          acc[i][j] = __builtin_amdgcn_mfma_f32_32x32x16_bf16(af[i], bfr[j], acc[i][j], 0, 0, 0);
    }
    __syncthreads();
  }

  // epilogue: C/D layout col=lane&31, row=(reg&3)+8*(reg>>2)+4*(lane>>5)
  const int rbase = rowBase + wr * 128 + 4 * khalf;
  const int cbase = colBase + wc * 64;
  float c2v[2], bet[2];
  int gcol[2];
#pragma unroll
  for (int j = 0; j < 2; ++j) {
    gcol[j] = cbase + j * 32 + l31;
    c2v[j] = c2[gcol[j]];
    bet[j] = beta[gcol[j]];
  }
#pragma unroll
  for (int i = 0; i < 4; ++i) {
#pragma unroll
    for (int reg = 0; reg < 16; ++reg) {
      int grow = rbase + i * 32 + (reg & 3) + 8 * (reg >> 2);
      float x2v = x2[grow];
#pragma unroll
      for (int j = 0; j < 2; ++j) {
        float d = acc[i][j][reg];
        float sq = fmaxf(x2v + c2v[j] - 2.0f * d, 0.0f);
        float e = __expf(-bet[j] * __builtin_amdgcn_sqrtf(sq));
        Ebf[(size_t)grow * CC + gcol[j]] = f2bf(e);
      }
    }
  }
}

// ---- rowsum: one wave per row of Ebf ----
__global__ void rowsum_k(const u16* __restrict__ Ebf, float* __restrict__ rowsum) {
  const int lane = threadIdx.x & 63;
  const int row = blockIdx.x * 4 + (threadIdx.x >> 6);
  const uint4* p = reinterpret_cast<const uint4*>(Ebf + (size_t)row * CC);
  float s = 0.f;
#pragma unroll
  for (int it = 0; it < 8; ++it) {
    uint4 v = p[lane + 64 * it];
    unsigned w[4] = {v.x, v.y, v.z, v.w};
#pragma unroll
    for (int q = 0; q < 4; ++q) {
      union { unsigned u; float f; } lo, hi;
      lo.u = w[q] << 16;
      hi.u = w[q] & 0xffff0000u;
      s += lo.f + hi.f;
    }
  }
#pragma unroll
  for (int off = 1; off < 64; off <<= 1) s += __shfl_xor(s, off);
  if (lane == 0) rowsum[row] = s;
}

// ---- GEMM2: out = (E @ W^T)/rowsum + bias; 128x128 tile, 2x2 of 32x32 ----
__global__ __launch_bounds__(256, 3)
void gemm2_out(const u16* __restrict__ Ebf, const u16* __restrict__ Wbf,
               const float* __restrict__ rowsum, const float* __restrict__ bias,
               float* __restrict__ out) {
  constexpr int Kd = CC;
  __shared__ __align__(16) char smem[32768];

  const int t = threadIdx.x;
  const int lane = t & 63;
  const int wave = t >> 6;
  const int wr = wave >> 1, wc = wave & 1;
  const int l31 = lane & 31, khalf = lane >> 5;

  const int rowBase = blockIdx.y * 128;
  const int colBase = blockIdx.x * 128;

  f32x16 acc[2][2];
#pragma unroll
  for (int i = 0; i < 2; ++i)
#pragma unroll
    for (int j = 0; j < 2; ++j) acc[i][j] = 0.f;

  const int sr = t >> 3;
  const int fstage = ((t >> 3) & 7) ^ (((t >> 6) & 3) << 1);
  const int srcChunkOff = ((t & 7) ^ fstage) * 8;
  const u16* gA0 = Ebf + (size_t)(rowBase + sr) * Kd + srcChunkOff;
  const u16* gB0 = Wbf + (size_t)(colBase + sr) * Kd + srcChunkOff;
  const int fv = (l31 & 7) ^ (((l31 >> 3) & 3) << 1);

  for (int kc = 0; kc < Kd; kc += 64) {
#pragma unroll
    for (int it = 0; it < 4; ++it) {
      const u16* ga = gA0 + (size_t)(32 * it) * Kd + kc;
      __builtin_amdgcn_global_load_lds((gvp_t)ga, (lvp_t)(smem + it * 4096 + t * 16), 16, 0, 0);
    }
#pragma unroll
    for (int it = 0; it < 4; ++it) {
      const u16* gb = gB0 + (size_t)(32 * it) * Kd + kc;
      __builtin_amdgcn_global_load_lds((gvp_t)gb, (lvp_t)(smem + 16384 + it * 4096 + t * 16), 16, 0, 0);
    }
    __syncthreads();
#pragma unroll
    for (int ks = 0; ks < 4; ++ks) {
      const int slot = ((ks * 2 + khalf) ^ fv) * 16;
      bf16x8 af[2], bfr[2];
#pragma unroll
      for (int i = 0; i < 2; ++i) {
        int r = wr * 64 + i * 32 + l31;
        af[i] = *(const bf16x8*)(smem + r * 128 + slot);
      }
#pragma unroll
      for (int j = 0; j < 2; ++j) {
        int r = wc * 64 + j * 32 + l31;
        bfr[j] = *(const bf16x8*)(smem + 16384 + r * 128 + slot);
      }
#pragma unroll
      for (int j = 0; j < 2; ++j)
#pragma unroll
        for (int i = 0; i < 2; ++i)
          acc[i][j] = __builtin_amdgcn_mfma_f32_32x32x16_bf16(af[i], bfr[j], acc[i][j], 0, 0, 0);
    }
    __syncthreads();
  }

  const int rbase = rowBase + wr * 64 + 4 * khalf;
  const int cbase = colBase + wc * 64;
  int gcol[2];
  float bv[2];
#pragma unroll
  for (int j = 0; j < 2; ++j) {
    gcol[j] = cbase + j * 32 + l31;
    bv[j] = (gcol[j] < KK) ? bias[gcol[j]] : 0.f;
  }
#pragma unroll
  for (int i = 0; i < 2; ++i) {
#pragma unroll
    for (int reg = 0; reg < 16; ++reg) {
      int grow = rbase + i * 32 + (reg & 3) + 8 * (reg >> 2);
      float inv = 1.0f / rowsum[grow];
#pragma unroll
      for (int j = 0; j < 2; ++j) {
        if (gcol[j] < KK)
          out[(size_t)grow * KK + gcol[j]] = acc[i][j][reg] * inv + bv[j];
      }
    }
  }
}

// ---- workspace layout (bytes) ----
#define OFF_XB 0u                    // 8192*2048*2 = 33554432
#define OFF_CB 33554432u             // 4096*2048*2 = 16777216
#define OFF_WB 50331648u             // 1024*4096*2 = 8388608
#define OFF_EB 58720256u             // 8192*4096*2 = 67108864
#define OFF_X2 125829120u            // 8192*4
#define OFF_C2 125861888u            // 4096*4
#define OFF_RS 125878272u            // 8192*4

extern "C" void kernel_launch(void* const* d_in, const int* in_sizes, int n_in,
                              void* d_out, int out_size, void* d_ws, size_t ws_size,
                              hipStream_t stream) {
  const float* x = (const float*)d_in[0];
  const float* cen = (const float*)d_in[1];
  const float* beta = (const float*)d_in[2];
  const float* W = (const float*)d_in[3];
  const float* bias = (const float*)d_in[4];
  float* out = (float*)d_out;
  char* ws = (char*)d_ws;

  u16* xb = (u16*)(ws + OFF_XB);
  u16* cb = (u16*)(ws + OFF_CB);
  u16* wb = (u16*)(ws + OFF_WB);
  u16* eb = (u16*)(ws + OFF_EB);
  float* x2 = (float*)(ws + OFF_X2);
  float* c2 = (float*)(ws + OFF_C2);
  float* rowsum = (float*)(ws + OFF_RS);

  prep_norm_cast<<<BB + CC, 256, 0, stream>>>(x, cen, xb, cb, x2, c2);
  prep_wcast<<<KP, 256, 0, stream>>>(W, wb);
  gemm1_rbf<<<dim3(CC / 128, BB / 256), 256, 0, stream>>>(xb, cb, x2, c2, beta, eb);
  rowsum_k<<<BB / 4, 256, 0, stream>>>(eb, rowsum);
  gemm2_out<<<dim3(KP / 128, BB / 128), 256, 0, stream>>>(eb, wb, rowsum, bias, out);
}